// Round 20
// baseline (569.452 us; speedup 1.0000x reference)
//
#include <hip/hip_runtime.h>
#include <hip/hip_bf16.h>

#define MROWS 4096      // B*T
#define KDIM 1024       // H
#define NVOCAB 32000    // V
#define MTILES (MROWS / 128)   // 32 (128-row pack tiles)
#define NTILES (NVOCAB / 128)  // 250 (128-row pack tiles)
#define NCH 250                // 128-col output chunks
#define KT 16                  // K-steps of 64
#define BETA 0.1f

typedef __attribute__((ext_vector_type(8))) int i8v;
typedef __attribute__((ext_vector_type(16))) float f16v;

__device__ inline void gload16(const void* g, void* l) {
  __builtin_amdgcn_global_load_lds(
      (const __attribute__((address_space(1))) void*)g,
      (__attribute__((address_space(3))) void*)l, 16, 0, 0);
}

// fp32 -> fp8 e4m3 pack, CONTIGUOUS-LANE image layout (identical to r19).
// Per (128-row tile, 64-col step): 8192-B image = 4 row-blocks x 2048 B.
// Within a block, lane l's 32 fp8 are CONTIGUOUS at [l*32, l*32+32):
//   row = tile*128 + blk*32 + (l&31), k = step*64 + (l>>5)*32 .. +32
// chunk c (16B): blk=c>>7, r2=c&127, l=r2>>1, h=r2&1
__global__ void cvt_all(const float4* __restrict__ x, const float4* __restrict__ rx,
                        const float4* __restrict__ W, const float4* __restrict__ rW,
                        uint4* __restrict__ xq, uint4* __restrict__ rxq,
                        uint4* __restrict__ Wq, uint4* __restrict__ rWq) {
  const int NA = MTILES * KT * 512;    // 262144 chunks
  const int NW = NTILES * KT * 512;    // 2048000 chunks
  const int total = 2 * NA + 2 * NW;
  for (int g = blockIdx.x * 256 + threadIdx.x; g < total; g += gridDim.x * 256) {
    const float4* s; uint4* d; int j;
    if (g < NA)               { s = x;  d = xq;  j = g; }
    else if (g < 2 * NA)      { s = rx; d = rxq; j = g - NA; }
    else if (g < 2 * NA + NW) { s = W;  d = Wq;  j = g - 2 * NA; }
    else                      { s = rW; d = rWq; j = g - 2 * NA - NW; }
    const int tile = j >> 13;
    const int rem  = j & 8191;
    const int step = rem >> 9;
    const int c    = rem & 511;
    const int blk = c >> 7, r2 = c & 127;
    const int l = r2 >> 1, h = r2 & 1;
    const int row = tile * 128 + blk * 32 + (l & 31);
    const int col = step * 64 + (r2 >> 6) * 32 + h * 16;
    const float4* p = s + ((size_t)row * KDIM + col) / 4;
    float4 a = p[0], b = p[1], e = p[2], f = p[3];
    unsigned w0 = __builtin_amdgcn_cvt_pk_fp8_f32(a.x, a.y, 0, false);
    w0 = __builtin_amdgcn_cvt_pk_fp8_f32(a.z, a.w, w0, true);
    unsigned w1 = __builtin_amdgcn_cvt_pk_fp8_f32(b.x, b.y, 0, false);
    w1 = __builtin_amdgcn_cvt_pk_fp8_f32(b.z, b.w, w1, true);
    unsigned w2 = __builtin_amdgcn_cvt_pk_fp8_f32(e.x, e.y, 0, false);
    w2 = __builtin_amdgcn_cvt_pk_fp8_f32(e.z, e.w, w2, true);
    unsigned w3 = __builtin_amdgcn_cvt_pk_fp8_f32(f.x, f.y, 0, false);
    w3 = __builtin_amdgcn_cvt_pk_fp8_f32(f.z, f.w, w3, true);
    d[j] = make_uint4(w0, w1, w2, w3);
  }
}

// fragment = single contiguous 32B load (global or LDS), k-order preserved
__device__ inline i8v ldfrag(const unsigned char* p) {
  return *(const i8v*)p;
}

// B-PANEL-IN-LDS GEMM: block = 8 waves (512 thr), tile 512m x 128n; the
// block's ENTIRE packed B panel (16 steps x 8192 B = 128 KB, contiguous in
// the packed image) is staged to LDS once (linear global_load_lds, ONE
// barrier), then a barrier-free K-loop per wave (64m x 128n, 2x4 of
// 32x32x64 MX-fp8): A (4 dwordx4) from global, B (4 frags) from LDS.
// B L2-traffic drops 8x (staged once per 512 rows). Waves own disjoint M
// rows -> epilogue needs no cross-wave reduction (no extra LDS).
// grid = (2000, 2): mblk = bid&7 (=XCD: A panel L2-resident), n128 = bid>>3.
__global__ __launch_bounds__(512, 2) void gemm_lse(
    const unsigned char* __restrict__ xq, const unsigned char* __restrict__ rxq,
    const unsigned char* __restrict__ Wq, const unsigned char* __restrict__ rWq,
    const int* __restrict__ y,
    float2* __restrict__ partials,  // [2][NCH][MROWS]
    float* __restrict__ tgt)        // [2][MROWS]
{
  const int bid = blockIdx.x;       // 0..1999
  const int bz  = blockIdx.y;       // model
  const int mblk = bid & 7;         // 0..7 (512-row block) == XCD
  const int n128 = bid >> 3;        // 0..249
  const int n0 = n128 * 128;

  const unsigned char* Aq = bz ? rxq : xq;
  const unsigned char* Bq = bz ? rWq : Wq;

  const int tid = threadIdx.x;
  const int lane = tid & 63;
  const int w = tid >> 6;            // 0..7
  const int l31 = lane & 31, hi5 = lane >> 5;

  __shared__ __align__(16) unsigned char Bs[KT * 8192];   // 128 KB

  // ---- stage whole B panel: 8192 linear 16B chunks (16 per thread) ----
  const unsigned char* Bpanel = Bq + (size_t)n128 * (KT * 8192);
#pragma unroll
  for (int j = 0; j < 16; ++j) {
    const int c = tid + j * 512;
    gload16(Bpanel + c * 16, &Bs[c * 16]);
  }

  // wave's A base: rows m0w..m0w+63
  const int m0w = mblk * 512 + w * 64;
  const unsigned char* pa = Aq + (size_t)(m0w >> 7) * (KT * 8192)
                            + ((m0w >> 6) & 1) * 4096 + lane * 32;

  f16v acc[2][4];
#pragma unroll
  for (int i = 0; i < 2; ++i)
#pragma unroll
    for (int j = 0; j < 4; ++j) acc[i][j] = (f16v)(0.f);

  __syncthreads();   // the ONLY barrier: B panel resident in LDS

  const unsigned char* pb = &Bs[lane * 32];

#pragma unroll 2
  for (int s = 0; s < KT; ++s) {
    i8v a0 = ldfrag(pa);
    i8v a1 = ldfrag(pa + 2048);
    i8v b0 = ldfrag(pb);
    i8v b1 = ldfrag(pb + 2048);
    i8v b2 = ldfrag(pb + 4096);
    i8v b3 = ldfrag(pb + 6144);
    acc[0][0] = __builtin_amdgcn_mfma_scale_f32_32x32x64_f8f6f4(a0, b0, acc[0][0], 0, 0, 0, 127, 0, 127);
    acc[0][1] = __builtin_amdgcn_mfma_scale_f32_32x32x64_f8f6f4(a0, b1, acc[0][1], 0, 0, 0, 127, 0, 127);
    acc[0][2] = __builtin_amdgcn_mfma_scale_f32_32x32x64_f8f6f4(a0, b2, acc[0][2], 0, 0, 0, 127, 0, 127);
    acc[0][3] = __builtin_amdgcn_mfma_scale_f32_32x32x64_f8f6f4(a0, b3, acc[0][3], 0, 0, 0, 127, 0, 127);
    acc[1][0] = __builtin_amdgcn_mfma_scale_f32_32x32x64_f8f6f4(a1, b0, acc[1][0], 0, 0, 0, 127, 0, 127);
    acc[1][1] = __builtin_amdgcn_mfma_scale_f32_32x32x64_f8f6f4(a1, b1, acc[1][1], 0, 0, 0, 127, 0, 127);
    acc[1][2] = __builtin_amdgcn_mfma_scale_f32_32x32x64_f8f6f4(a1, b2, acc[1][2], 0, 0, 0, 127, 0, 127);
    acc[1][3] = __builtin_amdgcn_mfma_scale_f32_32x32x64_f8f6f4(a1, b3, acc[1][3], 0, 0, 0, 127, 0, 127);
    pa += 8192;
    pb += 8192;
  }

  // Epilogue, fully in-wave. 32x32 D layout (HW-verified): col = ni*32+(lane&31),
  // row = mi*32 + (r&3)+8*(r>>2)+4*hi5. A row's 128 cols live in one 32-lane
  // half (one value per ni per lane) -> shfl_xor d<32 reduces within the half.
  int yreg = y[m0w + lane];
#pragma unroll
  for (int mi = 0; mi < 2; ++mi) {
#pragma unroll
    for (int r = 0; r < 16; ++r) {
      float v0 = acc[mi][0][r], v1 = acc[mi][1][r], v2 = acc[mi][2][r], v3 = acc[mi][3][r];
      float mx = fmaxf(fmaxf(v0, v1), fmaxf(v2, v3));
#pragma unroll
      for (int d = 1; d < 32; d <<= 1) mx = fmaxf(mx, __shfl_xor(mx, d));
      float ex = __expf(v0 - mx) + __expf(v1 - mx) + __expf(v2 - mx) + __expf(v3 - mx);
#pragma unroll
      for (int d = 1; d < 32; d <<= 1) ex += __shfl_xor(ex, d);
      int rowInBlock = mi * 32 + (r & 3) + 8 * (r >> 2) + 4 * hi5;
      int grow = m0w + rowInBlock;
      if (l31 == 0)
        partials[((size_t)bz * NCH + n128) * MROWS + grow] = make_float2(mx, ex);
      int yv = __shfl(yreg, rowInBlock);
      int cl = yv - n0;
      if (cl >= 0 && cl < 128 && (cl & 31) == l31) {
        int ni = cl >> 5;
        float tv = ni == 0 ? v0 : ni == 1 ? v1 : ni == 2 ? v2 : v3;
        tgt[(size_t)bz * MROWS + grow] = tv;
      }
    }
  }
}

// merge partials per row -> lse -> per-example sums (atomic).
// grid = 32 blocks (model x 16), 256 thr, one row per thread.
__global__ void rowred(const float2* __restrict__ partials, const float* __restrict__ tgt,
                       const int* __restrict__ y, float* __restrict__ sums) {
  const int model = blockIdx.x >> 4;
  const int rb = blockIdx.x & 15;
  const int row = rb * 256 + threadIdx.x;
  const int b = row >> 10;          // all rows of this block share one example
  float M = -INFINITY, S = 0.f;
  const float2* p = partials + (size_t)model * NCH * MROWS + row;
#pragma unroll 5
  for (int j = 0; j < NCH; ++j) {
    float2 v = p[(size_t)j * MROWS];
    float Mn = fmaxf(M, v.x);
    S = S * __expf(M - Mn) + v.y * __expf(v.x - Mn);
    M = Mn;
  }
  int yv = y[row];
  float val = 0.f, c = 0.f;
  if (yv != -100) {
    val = tgt[(size_t)model * MROWS + row] - (M + __logf(S));
    c = 1.f;
  }
#pragma unroll
  for (int d = 1; d < 64; d <<= 1) { val += __shfl_xor(val, d); c += __shfl_xor(c, d); }
  __shared__ float sv[4], sc[4];
  const int w = threadIdx.x >> 6;
  if ((threadIdx.x & 63) == 0) { sv[w] = val; sc[w] = c; }
  __syncthreads();
  if (threadIdx.x == 0) {
    float s = sv[0] + sv[1] + sv[2] + sv[3];
    float cc = sc[0] + sc[1] + sc[2] + sc[3];
    atomicAdd(&sums[model * 4 + b], s);
    atomicAdd(&sums[8 + model * 4 + b], cc);
  }
}

__global__ void finalk(const float* __restrict__ sums, const int* __restrict__ pref,
                       float* __restrict__ out) {
  if (threadIdx.x == 0 && blockIdx.x == 0) {
    float acc = 0.f;
    for (int b = 0; b < 4; ++b) {
      float lp = sums[b] / sums[8 + b];           // policy
      float lr = sums[4 + b] / sums[12 + b];      // ref
      float z = BETA * (lp - lr);
      float sig = 1.f / (1.f + __expf(-z));
      acc += (pref[b] != 0) ? (1.f - sig) : sig;
    }
    out[0] = acc * 0.25f;
  }
}

extern "C" void kernel_launch(void* const* d_in, const int* in_sizes, int n_in,
                              void* d_out, int out_size, void* d_ws, size_t ws_size,
                              hipStream_t stream) {
  const float* x    = (const float*)d_in[0];
  const float* rx   = (const float*)d_in[1];
  const int*   y    = (const int*)d_in[2];
  const int*   pref = (const int*)d_in[3];
  const float* W    = (const float*)d_in[4];
  const float* rW   = (const float*)d_in[5];
  float* out = (float*)d_out;

  char* ws = (char*)d_ws;
  const size_t SZ_X = (size_t)MROWS * KDIM;        // 4 MB (fp8 packed)
  const size_t SZ_W = (size_t)NVOCAB * KDIM;       // 32 MB (fp8 packed)
  unsigned char* xq  = (unsigned char*)(ws);
  unsigned char* rxq = (unsigned char*)(ws + SZ_X);
  unsigned char* Wq  = (unsigned char*)(ws + 2 * SZ_X);
  unsigned char* rWq = (unsigned char*)(ws + 2 * SZ_X + SZ_W);
  float2* partials = (float2*)(ws + 2 * SZ_X + 2 * SZ_W);              // 16.4 MB
  float*  tgt      = (float*)(ws + 2 * SZ_X + 2 * SZ_W + (size_t)2 * NCH * MROWS * 8);
  float*  sums     = (float*)(ws + 2 * SZ_X + 2 * SZ_W + (size_t)2 * NCH * MROWS * 8 + 2 * MROWS * 4);

  cvt_all<<<dim3(2048), 256, 0, stream>>>((const float4*)x, (const float4*)rx,
                                          (const float4*)W, (const float4*)rW,
                                          (uint4*)xq, (uint4*)rxq, (uint4*)Wq, (uint4*)rWq);

  hipMemsetAsync(sums, 0, 16 * sizeof(float), stream);

  gemm_lse<<<dim3(2000, 2), 512, 0, stream>>>(xq, rxq, Wq, rWq, y, partials, tgt);
  rowred<<<dim3(32), 256, 0, stream>>>(partials, tgt, y, sums);
  finalk<<<dim3(1), 64, 0, stream>>>(sums, pref, out);
}

// Round 21
// 363.873 us; speedup vs baseline: 1.5650x; 1.5650x over previous
//
#include <hip/hip_runtime.h>
#include <hip/hip_bf16.h>

#define MROWS 4096      // B*T
#define KDIM 1024       // H
#define NVOCAB 32000    // V
#define MTILES (MROWS / 128)   // 32 (128-row pack tiles)
#define NTILES (NVOCAB / 128)  // 250 (128-row pack tiles)
#define NCH 250                // 128-col output chunks
#define KT 16                  // K-steps of 64
#define BETA 0.1f
#define WSCALE 32.0f
#define INVWSCALE 0.03125f

typedef __attribute__((ext_vector_type(4))) int i4v;
typedef __attribute__((ext_vector_type(8))) int i8v;
typedef __attribute__((ext_vector_type(16))) float f16v;

// fp4 e2m1 quantizer, round-to-nearest: mags {0,.5,1,1.5,2,3,4,6}, code=idx|sign<<3
__device__ inline unsigned q4(float f) {
  float af = fabsf(f);
  unsigned idx = (af >= 0.25f) + (af >= 0.75f) + (af >= 1.25f) + (af >= 1.75f)
               + (af >= 2.5f) + (af >= 3.5f) + (af >= 5.0f);
  return idx | (f < 0.f ? 8u : 0u);
}

// fp32 -> fp4 e2m1 pack, CONTIGUOUS-LANE image layout.
// Per (128-row tile, 64-col step): 4096-B image = 4 row-blocks x 1024 B.
// Lane l's 32 fp4 are CONTIGUOUS at [l*16, l*16+16):
//   row = tile*128 + blk*32 + (l&31), k = step*64 + (l>>5)*32 .. +32
// Output unit = uint (8 fp4, k ascending, LOW NIBBLE FIRST).
// uint j: tile=j>>14, rem=j&16383, step=rem>>10, c=rem&1023,
//         blk=c>>8, r=c&255, l=r>>2, u=r&3
// W tensors are pre-scaled by 32 (sigma 1/32 -> 1, matches e2m1 grid);
// GEMM epilogue multiplies acc by 1/32.
__global__ void cvt_all(const float4* __restrict__ x, const float4* __restrict__ rx,
                        const float4* __restrict__ W, const float4* __restrict__ rW,
                        unsigned* __restrict__ xq, unsigned* __restrict__ rxq,
                        unsigned* __restrict__ Wq, unsigned* __restrict__ rWq) {
  const int NA = MTILES * KT * 1024;   // 524288 uints
  const int NW = NTILES * KT * 1024;   // 4096000 uints
  const int total = 2 * NA + 2 * NW;
  for (int g = blockIdx.x * 256 + threadIdx.x; g < total; g += gridDim.x * 256) {
    const float4* s; unsigned* d; int j; float sc;
    if (g < NA)               { s = x;  d = xq;  j = g;               sc = 1.f; }
    else if (g < 2 * NA)      { s = rx; d = rxq; j = g - NA;          sc = 1.f; }
    else if (g < 2 * NA + NW) { s = W;  d = Wq;  j = g - 2 * NA;      sc = WSCALE; }
    else                      { s = rW; d = rWq; j = g - 2 * NA - NW; sc = WSCALE; }
    const int tile = j >> 14;
    const int rem  = j & 16383;
    const int step = rem >> 10;
    const int c    = rem & 1023;
    const int blk = c >> 8, r = c & 255;
    const int l = r >> 2, u = r & 3;
    const int row = tile * 128 + blk * 32 + (l & 31);
    const int kbase = step * 64 + (l >> 5) * 32 + u * 8;
    const float4* p = s + ((size_t)row * KDIM + kbase) / 4;
    float4 a = p[0], b = p[1];
    unsigned o = q4(a.x * sc)        | (q4(a.y * sc) << 4)
               | (q4(a.z * sc) << 8) | (q4(a.w * sc) << 12)
               | (q4(b.x * sc) << 16)| (q4(b.y * sc) << 20)
               | (q4(b.z * sc) << 24)| (q4(b.w * sc) << 28);
    d[j] = o;
  }
}

// fragment = single contiguous 16B load (4 regs used by fp4 MFMA; high 4 zero)
__device__ inline i8v ldfrag(const unsigned char* p) {
  i4v lo = *(const i4v*)p;
  i4v z = (i4v)(0);
  return __builtin_shufflevector(lo, z, 0, 1, 2, 3, 4, 5, 6, 7);
}

// BARRIER-FREE fat-tile GEMM, MX-fp4 (r19 structure, 2x MFMA rate, half bytes):
// 1 wave/block, 64m x 128n (2x4 of 32x32x64 f8f6f4 FMT=FP4), 6 loads : 8 MFMAs
// per K-step, A/B direct from pre-packed global, unroll 2, compiler pipelines.
// grid = (16000, 2): xcd=bid&7, idx=bid>>3; n128=idx>>3 (8 blocks/XCD share
// one 128-col W panel), m64=xcd*8+(idx&7).
__global__ __launch_bounds__(64, 2) void gemm_lse(
    const unsigned char* __restrict__ xq, const unsigned char* __restrict__ rxq,
    const unsigned char* __restrict__ Wq, const unsigned char* __restrict__ rWq,
    const int* __restrict__ y,
    float2* __restrict__ partials,  // [2][NCH][MROWS]
    float* __restrict__ tgt)        // [2][MROWS]
{
  const int bid = blockIdx.x;       // 0..15999
  const int bz  = blockIdx.y;       // model
  const int xcd = bid & 7;
  const int idx = bid >> 3;         // 0..1999
  const int n128 = idx >> 3;        // 0..249
  const int m64  = xcd * 8 + (idx & 7);  // 0..63
  const int m0 = m64 * 64, n0 = n128 * 128;

  const unsigned char* Ap = (bz ? rxq : xq) + (size_t)(m64 >> 1) * (KT * 4096)
                            + (m64 & 1) * 2048;
  const unsigned char* Bp = (bz ? rWq : Wq) + (size_t)n128 * (KT * 4096);

  const int lane = threadIdx.x;
  const int l31 = lane & 31, hi5 = lane >> 5;

  const unsigned char* pa = Ap + lane * 16;
  const unsigned char* pb = Bp + lane * 16;

  f16v acc[2][4];
#pragma unroll
  for (int i = 0; i < 2; ++i)
#pragma unroll
    for (int j = 0; j < 4; ++j) acc[i][j] = (f16v)(0.f);

#pragma unroll 2
  for (int s = 0; s < KT; ++s) {
    i8v a0 = ldfrag(pa);
    i8v a1 = ldfrag(pa + 1024);
    i8v b0 = ldfrag(pb);
    i8v b1 = ldfrag(pb + 1024);
    i8v b2 = ldfrag(pb + 2048);
    i8v b3 = ldfrag(pb + 3072);
    acc[0][0] = __builtin_amdgcn_mfma_scale_f32_32x32x64_f8f6f4(a0, b0, acc[0][0], 4, 4, 0, 127, 0, 127);
    acc[0][1] = __builtin_amdgcn_mfma_scale_f32_32x32x64_f8f6f4(a0, b1, acc[0][1], 4, 4, 0, 127, 0, 127);
    acc[0][2] = __builtin_amdgcn_mfma_scale_f32_32x32x64_f8f6f4(a0, b2, acc[0][2], 4, 4, 0, 127, 0, 127);
    acc[0][3] = __builtin_amdgcn_mfma_scale_f32_32x32x64_f8f6f4(a0, b3, acc[0][3], 4, 4, 0, 127, 0, 127);
    acc[1][0] = __builtin_amdgcn_mfma_scale_f32_32x32x64_f8f6f4(a1, b0, acc[1][0], 4, 4, 0, 127, 0, 127);
    acc[1][1] = __builtin_amdgcn_mfma_scale_f32_32x32x64_f8f6f4(a1, b1, acc[1][1], 4, 4, 0, 127, 0, 127);
    acc[1][2] = __builtin_amdgcn_mfma_scale_f32_32x32x64_f8f6f4(a1, b2, acc[1][2], 4, 4, 0, 127, 0, 127);
    acc[1][3] = __builtin_amdgcn_mfma_scale_f32_32x32x64_f8f6f4(a1, b3, acc[1][3], 4, 4, 0, 127, 0, 127);
    pa += 4096;
    pb += 4096;
  }

  // Epilogue, fully in-wave; acc scaled by 1/32 (undoes W pre-scale).
  // 32x32 D layout (HW-verified): col = ni*32+(lane&31),
  // row = mi*32 + (r&3)+8*(r>>2)+4*hi5. Row's 128 cols live in one 32-lane
  // half -> shfl_xor d<32 reduces within the half.
  int yreg = y[m0 + lane];
#pragma unroll
  for (int mi = 0; mi < 2; ++mi) {
#pragma unroll
    for (int r = 0; r < 16; ++r) {
      float v0 = acc[mi][0][r] * INVWSCALE, v1 = acc[mi][1][r] * INVWSCALE;
      float v2 = acc[mi][2][r] * INVWSCALE, v3 = acc[mi][3][r] * INVWSCALE;
      float mx = fmaxf(fmaxf(v0, v1), fmaxf(v2, v3));
#pragma unroll
      for (int d = 1; d < 32; d <<= 1) mx = fmaxf(mx, __shfl_xor(mx, d));
      float ex = __expf(v0 - mx) + __expf(v1 - mx) + __expf(v2 - mx) + __expf(v3 - mx);
#pragma unroll
      for (int d = 1; d < 32; d <<= 1) ex += __shfl_xor(ex, d);
      int rowInBlock = mi * 32 + (r & 3) + 8 * (r >> 2) + 4 * hi5;
      int grow = m0 + rowInBlock;
      if (l31 == 0)
        partials[((size_t)bz * NCH + n128) * MROWS + grow] = make_float2(mx, ex);
      int yv = __shfl(yreg, rowInBlock);
      int cl = yv - n0;
      if (cl >= 0 && cl < 128 && (cl & 31) == l31) {
        int ni = cl >> 5;
        float tv = ni == 0 ? v0 : ni == 1 ? v1 : ni == 2 ? v2 : v3;
        tgt[(size_t)bz * MROWS + grow] = tv;
      }
    }
  }
}

// merge partials per row -> lse -> per-example sums (atomic).
// grid = 32 blocks (model x 16), 256 thr, one row per thread.
__global__ void rowred(const float2* __restrict__ partials, const float* __restrict__ tgt,
                       const int* __restrict__ y, float* __restrict__ sums) {
  const int model = blockIdx.x >> 4;
  const int rb = blockIdx.x & 15;
  const int row = rb * 256 + threadIdx.x;
  const int b = row >> 10;          // all rows of this block share one example
  float M = -INFINITY, S = 0.f;
  const float2* p = partials + (size_t)model * NCH * MROWS + row;
#pragma unroll 5
  for (int j = 0; j < NCH; ++j) {
    float2 v = p[(size_t)j * MROWS];
    float Mn = fmaxf(M, v.x);
    S = S * __expf(M - Mn) + v.y * __expf(v.x - Mn);
    M = Mn;
  }
  int yv = y[row];
  float val = 0.f, c = 0.f;
  if (yv != -100) {
    val = tgt[(size_t)model * MROWS + row] - (M + __logf(S));
    c = 1.f;
  }
#pragma unroll
  for (int d = 1; d < 64; d <<= 1) { val += __shfl_xor(val, d); c += __shfl_xor(c, d); }
  __shared__ float sv[4], sc[4];
  const int w = threadIdx.x >> 6;
  if ((threadIdx.x & 63) == 0) { sv[w] = val; sc[w] = c; }
  __syncthreads();
  if (threadIdx.x == 0) {
    float s = sv[0] + sv[1] + sv[2] + sv[3];
    float cc = sc[0] + sc[1] + sc[2] + sc[3];
    atomicAdd(&sums[model * 4 + b], s);
    atomicAdd(&sums[8 + model * 4 + b], cc);
  }
}

__global__ void finalk(const float* __restrict__ sums, const int* __restrict__ pref,
                       float* __restrict__ out) {
  if (threadIdx.x == 0 && blockIdx.x == 0) {
    float acc = 0.f;
    for (int b = 0; b < 4; ++b) {
      float lp = sums[b] / sums[8 + b];           // policy
      float lr = sums[4 + b] / sums[12 + b];      // ref
      float z = BETA * (lp - lr);
      float sig = 1.f / (1.f + __expf(-z));
      acc += (pref[b] != 0) ? (1.f - sig) : sig;
    }
    out[0] = acc * 0.25f;
  }
}

extern "C" void kernel_launch(void* const* d_in, const int* in_sizes, int n_in,
                              void* d_out, int out_size, void* d_ws, size_t ws_size,
                              hipStream_t stream) {
  const float* x    = (const float*)d_in[0];
  const float* rx   = (const float*)d_in[1];
  const int*   y    = (const int*)d_in[2];
  const int*   pref = (const int*)d_in[3];
  const float* W    = (const float*)d_in[4];
  const float* rW   = (const float*)d_in[5];
  float* out = (float*)d_out;

  char* ws = (char*)d_ws;
  const size_t SZ_X = (size_t)MROWS * KDIM / 2;        // 2 MB (fp4 packed)
  const size_t SZ_W = (size_t)NVOCAB * KDIM / 2;       // 16 MB (fp4 packed)
  unsigned char* xq  = (unsigned char*)(ws);
  unsigned char* rxq = (unsigned char*)(ws + SZ_X);
  unsigned char* Wq  = (unsigned char*)(ws + 2 * SZ_X);
  unsigned char* rWq = (unsigned char*)(ws + 2 * SZ_X + SZ_W);
  float2* partials = (float2*)(ws + 2 * SZ_X + 2 * SZ_W);              // 16.4 MB
  float*  tgt      = (float*)(ws + 2 * SZ_X + 2 * SZ_W + (size_t)2 * NCH * MROWS * 8);
  float*  sums     = (float*)(ws + 2 * SZ_X + 2 * SZ_W + (size_t)2 * NCH * MROWS * 8 + 2 * MROWS * 4);

  cvt_all<<<dim3(2048), 256, 0, stream>>>((const float4*)x, (const float4*)rx,
                                          (const float4*)W, (const float4*)rW,
                                          (unsigned*)xq, (unsigned*)rxq,
                                          (unsigned*)Wq, (unsigned*)rWq);

  hipMemsetAsync(sums, 0, 16 * sizeof(float), stream);

  gemm_lse<<<dim3(16000, 2), 64, 0, stream>>>(xq, rxq, Wq, rWq, y, partials, tgt);
  rowred<<<dim3(32), 256, 0, stream>>>(partials, tgt, y, sums);
  finalk<<<dim3(1), 64, 0, stream>>>(sums, pref, out);
}